// Round 13
// baseline (127.166 us; speedup 1.0000x reference)
//
#include <hip/hip_runtime.h>

// Problem dims (fixed)
#define B_  2
#define S_  1024
#define D_  1024
#define H_  16
#define DH_ 64

typedef __attribute__((ext_vector_type(8))) short bf16x8;
typedef __attribute__((ext_vector_type(4))) float f32x4;

__device__ __forceinline__ unsigned short f2bf(float f) {
  unsigned int u = __float_as_uint(f);
  u += 0x7fff + ((u >> 16) & 1);   // round-to-nearest-even
  return (unsigned short)(u >> 16);
}

__device__ __forceinline__ void gload_lds16(const void* g, void* l) {
  __builtin_amdgcn_global_load_lds(
      (const __attribute__((address_space(1))) unsigned int*)g,
      (__attribute__((address_space(3))) unsigned int*)l, 16, 0, 0);
}

// ---------------------------------------------------------------------------
// Kernel 1: fp32 -> bf16 convert for x, W_qkv, W_out
// ---------------------------------------------------------------------------
__global__ __launch_bounds__(256)
void cvt_kernel(const float4* __restrict__ x, const float4* __restrict__ wq,
                const float4* __restrict__ wo, unsigned short* __restrict__ xb,
                unsigned short* __restrict__ wqb, unsigned short* __restrict__ wob) {
  constexpr int n1 = (B_*S_*D_) / 4;       // 524288
  constexpr int n2 = (3*D_*D_) / 4;        // 786432
  constexpr int n3 = (D_*D_) / 4;          // 262144
  for (int i = blockIdx.x*blockDim.x + threadIdx.x; i < n1+n2+n3;
       i += gridDim.x*blockDim.x) {
    const float4* src; unsigned short* dst; int off;
    if (i < n1)          { src = x;  dst = xb;  off = i; }
    else if (i < n1+n2)  { src = wq; dst = wqb; off = i - n1; }
    else                 { src = wo; dst = wob; off = i - n1 - n2; }
    float4 v = src[off];
    ushort4 r;
    r.x = f2bf(v.x); r.y = f2bf(v.y); r.z = f2bf(v.z); r.w = f2bf(v.w);
    *(ushort4*)&dst[off*4] = r;
  }
}

// ---------------------------------------------------------------------------
// gemm_bt2: C = A @ Bw^T.  BM x 128 tile, BK=64 (128B full-line staging),
// 4 waves (2x2), 2-buffer LDS, counted-vmcnt two-barrier loop (T3/T4) —
// sync structure verified R11 (passed replays). XCD supertile mapping (R12,
// index-only): XCD x owns chunk (x/CHN, x%CHN); per-XCD L2 working set
// gemm1 3.5MB / gemm2 2MB < 4MB L2. Rule-#21 swizzle both-sides.
// EPI=0: fp32 C. EPI=1: scatter Q(pre-scaled 0.125*log2e)/K/Vt bf16.
// ---------------------------------------------------------------------------
template<int BM, int M, int N, int K, int EPI, int CHM, int CHN>
__global__ __launch_bounds__(256)
void gemm_bt2(const unsigned short* __restrict__ A, const unsigned short* __restrict__ Bw,
              float* __restrict__ C, unsigned short* __restrict__ Qb,
              unsigned short* __restrict__ Kb, unsigned short* __restrict__ Vtb) {
  constexpr int NBN   = N / 128;
  constexpr int MT    = BM / 32;          // M-frags per wave
  constexpr int AG    = BM / 32;          // A-stage instrs per thread
  constexpr int NSTEP = K / 64;
  constexpr int PM    = (M/BM) / CHM;     // supertile dims per XCD chunk
  constexpr int PN    = NBN / CHN;
  __shared__ unsigned short As[2][BM*64];
  __shared__ unsigned short Bs[2][128*64];
  const int tid = threadIdx.x;
  const int xcd = blockIdx.x & 7, idx = blockIdx.x >> 3;
  const int mb = (xcd / CHN)*PM + idx / PN;
  const int nb = (xcd % CHN)*PN + idx % PN;
  const int wid = tid >> 6, lane = tid & 63;
  const int wr = wid >> 1, wc = wid & 1;
  const int lg = lane >> 4, lr = lane & 15;
  const int mrow = mb*BM, nrow = nb*128;
  const int rsw = lr & 7;

  const int srow = tid >> 3;                    // 0..31
  const int cg   = (tid & 7) ^ (srow & 7);      // pre-swizzled global chunk

  f32x4 acc[MT][4] = {};

  auto STAGE = [&](int t) {
    const int k0 = t*64, b = t & 1;
    #pragma unroll
    for (int g = 0; g < AG; ++g)
      gload_lds16(A + (size_t)(mrow + g*32 + srow)*K + k0 + cg*8,
                  &As[b][((g*32 + srow)*8 + (tid & 7))*8]);
    #pragma unroll
    for (int g = 0; g < 4; ++g)
      gload_lds16(Bw + (size_t)(nrow + g*32 + srow)*K + k0 + cg*8,
                  &Bs[b][((g*32 + srow)*8 + (tid & 7))*8]);
  };

  STAGE(0);
  for (int t = 0; t < NSTEP; ++t) {
    if (t + 1 < NSTEP) {
      STAGE(t+1);
      if constexpr (AG == 4) asm volatile("s_waitcnt vmcnt(8)" ::: "memory");
      else                   asm volatile("s_waitcnt vmcnt(6)" ::: "memory");
    } else {
      asm volatile("s_waitcnt vmcnt(0)" ::: "memory");
    }
    __builtin_amdgcn_s_barrier();
    __builtin_amdgcn_sched_barrier(0);
    const int b = t & 1;
    #pragma unroll
    for (int kk = 0; kk < 2; ++kk) {
      bf16x8 af[MT], bfr[4];
      #pragma unroll
      for (int m = 0; m < MT; ++m)
        af[m] = *(const bf16x8*)&As[b][(wr*(BM/2) + m*16 + lr)*64 + (((kk*4 + lg) ^ rsw)*8)];
      #pragma unroll
      for (int n = 0; n < 4; ++n)
        bfr[n] = *(const bf16x8*)&Bs[b][(wc*64 + n*16 + lr)*64 + (((kk*4 + lg) ^ rsw)*8)];
      #pragma unroll
      for (int m = 0; m < MT; ++m)
        #pragma unroll
        for (int n = 0; n < 4; ++n)
          acc[m][n] = __builtin_amdgcn_mfma_f32_16x16x32_bf16(af[m], bfr[n], acc[m][n], 0, 0, 0);
    }
    __builtin_amdgcn_sched_barrier(0);
    __builtin_amdgcn_s_barrier();
  }

  // Epilogue. C/D layout: row = lg*4 + i, col = lr  (verified m89/m91).
  #pragma unroll
  for (int mt = 0; mt < MT; ++mt) {
    const int m0 = mrow + wr*(BM/2) + mt*16 + lg*4;
    #pragma unroll
    for (int nt = 0; nt < 4; ++nt) {
      const int n = nrow + wc*64 + nt*16 + lr;
      f32x4 v = acc[mt][nt];
      if constexpr (EPI == 0) {
        #pragma unroll
        for (int i = 0; i < 4; ++i) C[(size_t)(m0 + i)*N + n] = v[i];
      } else {
        const int t3 = n >> 10, rem = n & 1023;
        const int hh = rem >> 6, dh = rem & 63;
        const int b = m0 >> 10, s0 = m0 & 1023;
        if (t3 == 2) {
          ushort4 pk;
          pk.x = f2bf(v[0]); pk.y = f2bf(v[1]); pk.z = f2bf(v[2]); pk.w = f2bf(v[3]);
          *(ushort4*)&Vtb[(size_t)((b*H_ + hh)*DH_ + dh)*S_ + s0] = pk;
        } else {
          unsigned short* dst = (t3 == 0) ? Qb : Kb;
          const float sc = (t3 == 0) ? 0.18033688f : 1.0f;   // 0.125 * log2(e)
          #pragma unroll
          for (int i = 0; i < 4; ++i)
            dst[(size_t)((b*H_ + hh)*S_ + s0 + i)*DH_ + dh] = f2bf(v[i]*sc);
        }
      }
    }
  }
}

// ---------------------------------------------------------------------------
// Flash attention v7 — EXACT R11-verified sync structure (3-buffer counted
// vmcnt(4), STAGE(t+2), one barrier/iter; passed graph-replay validation in
// R7/R10/R11; the R12 2-buffer variant raced and is abandoned).
// Max-free exp2 softmax (scale+log2e folded into Q), l via ones-MFMA,
// P packed with v_cvt_pk_bf16_f32, swapped QK^T / PV, XCD head swizzle.
// ---------------------------------------------------------------------------
__global__ __launch_bounds__(256, 2)
void attn_kernel(const unsigned short* __restrict__ Qb, const unsigned short* __restrict__ Kb,
                 const unsigned short* __restrict__ Vtb, unsigned short* __restrict__ AOb) {
  __shared__ unsigned short Ks[3][64*64];
  __shared__ unsigned short Vs[3][64*64];
  __shared__ unsigned short Pl[4][16*72];
  const int bid = blockIdx.x;
  const int xcd = bid & 7, rr = bid >> 3;
  const int qt = rr & 15;
  const int bh = (rr >> 4) * 8 + xcd;
  const int tid = threadIdx.x, wid = tid >> 6, lane = tid & 63;
  const int lg = lane >> 4, lr = lane & 15;
  const unsigned short* Q  = Qb  + (size_t)bh*S_*DH_;
  const unsigned short* Kp = Kb  + (size_t)bh*S_*DH_;
  const unsigned short* Vt = Vtb + (size_t)bh*DH_*S_;
  const int q0 = qt*64 + wid*16;

  bf16x8 qf0 = *(const bf16x8*)&Q[(size_t)(q0 + lr)*DH_ + lg*8];
  bf16x8 qf1 = *(const bf16x8*)&Q[(size_t)(q0 + lr)*DH_ + 32 + lg*8];
  const bf16x8 onesf = {(short)0x3F80, (short)0x3F80, (short)0x3F80, (short)0x3F80,
                        (short)0x3F80, (short)0x3F80, (short)0x3F80, (short)0x3F80};

  const int sr = tid >> 3;               // 0..31
  const int g0 = (tid & 7) ^ (sr & 7);   // pre-swizzled source chunk

  f32x4 o[4] = {};
  f32x4 ol = {};                         // l accumulator (all rows identical)
  const int rsw = lr & 7;

  auto STAGE = [&](int t) {
    const int j = t * 64, b = t % 3;
    gload_lds16(Kp + (size_t)(j + sr)*DH_      + g0*8, &Ks[b][tid*8]);
    gload_lds16(Kp + (size_t)(j + sr + 32)*DH_ + g0*8, &Ks[b][(256+tid)*8]);
    gload_lds16(Vt + (size_t)sr*S_      + j + g0*8,    &Vs[b][tid*8]);
    gload_lds16(Vt + (size_t)(sr+32)*S_ + j + g0*8,    &Vs[b][(256+tid)*8]);
  };

  STAGE(0);
  STAGE(1);
  for (int t = 0; t < 16; ++t) {
    if (t < 15) asm volatile("s_waitcnt vmcnt(4)" ::: "memory");
    else        asm volatile("s_waitcnt vmcnt(0)" ::: "memory");
    __builtin_amdgcn_s_barrier();
    __builtin_amdgcn_sched_barrier(0);
    if (t + 2 < 16) STAGE(t+2);
    const int buf = t % 3;
    // QK^T swapped: sv[f] = S^T rows (keys) 16f+lg*4+i, col q=lr
    f32x4 sv[4];
    __builtin_amdgcn_s_setprio(1);
    #pragma unroll
    for (int f = 0; f < 4; ++f) {
      bf16x8 ka = *(const bf16x8*)&Ks[buf][(16*f + lr)*64 + ((lg     ^ rsw)*8)];
      bf16x8 kb = *(const bf16x8*)&Ks[buf][(16*f + lr)*64 + (((lg+4) ^ rsw)*8)];
      f32x4 z = {};
      z     = __builtin_amdgcn_mfma_f32_16x16x32_bf16(ka, qf0, z, 0, 0, 0);
      sv[f] = __builtin_amdgcn_mfma_f32_16x16x32_bf16(kb, qf1, z, 0, 0, 0);
    }
    __builtin_amdgcn_s_setprio(0);
    // max-free softmax: P = 2^(s') directly (Q pre-scaled by 0.125*log2e)
    float p[16];
    #pragma unroll
    for (int f = 0; f < 4; ++f)
      #pragma unroll
      for (int i = 0; i < 4; ++i)
        asm("v_exp_f32 %0, %1" : "=v"(p[4*f + i]) : "v"(sv[f][i]));
    // P^T pack -> Pl[q=lr][key] via v_cvt_pk_bf16_f32
    #pragma unroll
    for (int f = 0; f < 4; ++f) {
      unsigned int w0, w1;
      asm("v_cvt_pk_bf16_f32 %0, %1, %2" : "=v"(w0) : "v"(p[4*f+0]), "v"(p[4*f+1]));
      asm("v_cvt_pk_bf16_f32 %0, %1, %2" : "=v"(w1) : "v"(p[4*f+2]), "v"(p[4*f+3]));
      uint2 wv; wv.x = w0; wv.y = w1;
      *(uint2*)&Pl[wid][lr*72 + f*16 + lg*4] = wv;
    }
    asm volatile("s_waitcnt lgkmcnt(0)" ::: "memory");
    __builtin_amdgcn_sched_barrier(0);
    // PV swapped: o[dt] += Vs[d][k] * P^T[k][q];  l via ones-MFMA
    __builtin_amdgcn_s_setprio(1);
    #pragma unroll
    for (int c = 0; c < 2; ++c) {
      bf16x8 pf = *(const bf16x8*)&Pl[wid][lr*72 + c*32 + lg*8];
      ol = __builtin_amdgcn_mfma_f32_16x16x32_bf16(onesf, pf, ol, 0, 0, 0);
      #pragma unroll
      for (int dt = 0; dt < 4; ++dt) {
        bf16x8 vfr = *(const bf16x8*)&Vs[buf][(dt*16 + lr)*64 + (((c*4 + lg) ^ rsw)*8)];
        o[dt] = __builtin_amdgcn_mfma_f32_16x16x32_bf16(vfr, pf, o[dt], 0, 0, 0);
      }
    }
    __builtin_amdgcn_s_setprio(0);
  }

  // epilogue: lane holds O^T[d = dt*16+lg*4+i][q = q0+lr]; l = ol[0]
  const float inv = 1.0f / ol[0];
  const int b = bh >> 4, hh = bh & 15;
  #pragma unroll
  for (int dt = 0; dt < 4; ++dt) {
    ushort4 pk;
    pk.x = f2bf(o[dt][0]*inv); pk.y = f2bf(o[dt][1]*inv);
    pk.z = f2bf(o[dt][2]*inv); pk.w = f2bf(o[dt][3]*inv);
    *(ushort4*)&AOb[(size_t)(b*S_ + q0 + lr)*D_ + hh*DH_ + dt*16 + lg*4] = pk;
  }
}

// ---------------------------------------------------------------------------
extern "C" void kernel_launch(void* const* d_in, const int* in_sizes, int n_in,
                              void* d_out, int out_size, void* d_ws, size_t ws_size,
                              hipStream_t stream) {
  const float* x  = (const float*)d_in[0];   // [B,S,D]
  const float* wq = (const float*)d_in[1];   // [3D,D]
  const float* wo = (const float*)d_in[2];   // [D,D]
  float* out = (float*)d_out;                // [B,S,D] fp32

  unsigned short* w = (unsigned short*)d_ws;
  unsigned short* xb  = w;                   // 2097152 bf16
  unsigned short* wqb = xb  + 2097152;       // 3145728
  unsigned short* wob = wqb + 3145728;       // 1048576
  unsigned short* qb  = wob + 1048576;       // 2097152  Q [B,H,S,DH] (pre-scaled)
  unsigned short* kb  = qb  + 2097152;       // 2097152  K [B,H,S,DH]
  unsigned short* vtb = kb  + 2097152;       // 2097152  V^T [B,H,DH,S]
  unsigned short* aob = vtb + 2097152;       // 2097152  attn out [B,S,D]

  cvt_kernel<<<dim3(1536), dim3(256), 0, stream>>>(
      (const float4*)x, (const float4*)wq, (const float4*)wo, xb, wqb, wob);

  // QKV projection: M=2048, N=3072, K=1024. 384 blocks of 128x128;
  // XCD chunk grid 2x4, supertile 8x6 (3.5MB/XCD working set).
  gemm_bt2<128, 2048, 3072, 1024, 1, 2, 4><<<dim3(384), dim3(256), 0, stream>>>(
      xb, wqb, nullptr, qb, kb, vtb);

  attn_kernel<<<dim3(512), dim3(256), 0, stream>>>(qb, kb, vtb, aob);

  // Output projection: M=2048, N=1024, K=1024. 256 blocks of 64x128;
  // XCD chunk grid 4x2, supertile 8x4 (2MB/XCD working set).
  gemm_bt2<64, 2048, 1024, 1024, 0, 4, 2><<<dim3(256), dim3(256), 0, stream>>>(
      aob, wob, out, nullptr, nullptr, nullptr);
}

// Round 14
// 121.036 us; speedup vs baseline: 1.0506x; 1.0506x over previous
//
#include <hip/hip_runtime.h>

// Problem dims (fixed)
#define B_  2
#define S_  1024
#define D_  1024
#define H_  16
#define DH_ 64

typedef __attribute__((ext_vector_type(8))) short bf16x8;
typedef __attribute__((ext_vector_type(4))) float f32x4;

__device__ __forceinline__ unsigned short f2bf(float f) {
  unsigned int u = __float_as_uint(f);
  u += 0x7fff + ((u >> 16) & 1);   // round-to-nearest-even
  return (unsigned short)(u >> 16);
}

__device__ __forceinline__ void gload_lds16(const void* g, void* l) {
  __builtin_amdgcn_global_load_lds(
      (const __attribute__((address_space(1))) unsigned int*)g,
      (__attribute__((address_space(3))) unsigned int*)l, 16, 0, 0);
}

// ---------------------------------------------------------------------------
// Kernel 1: fp32 -> bf16 convert for x, W_qkv, W_out
// ---------------------------------------------------------------------------
__global__ __launch_bounds__(256)
void cvt_kernel(const float4* __restrict__ x, const float4* __restrict__ wq,
                const float4* __restrict__ wo, unsigned short* __restrict__ xb,
                unsigned short* __restrict__ wqb, unsigned short* __restrict__ wob) {
  constexpr int n1 = (B_*S_*D_) / 4;       // 524288
  constexpr int n2 = (3*D_*D_) / 4;        // 786432
  constexpr int n3 = (D_*D_) / 4;          // 262144
  for (int i = blockIdx.x*blockDim.x + threadIdx.x; i < n1+n2+n3;
       i += gridDim.x*blockDim.x) {
    const float4* src; unsigned short* dst; int off;
    if (i < n1)          { src = x;  dst = xb;  off = i; }
    else if (i < n1+n2)  { src = wq; dst = wqb; off = i - n1; }
    else                 { src = wo; dst = wob; off = i - n1 - n2; }
    float4 v = src[off];
    ushort4 r;
    r.x = f2bf(v.x); r.y = f2bf(v.y); r.z = f2bf(v.z); r.w = f2bf(v.w);
    *(ushort4*)&dst[off*4] = r;
  }
}

// ---------------------------------------------------------------------------
// gemm_bt2: C = A @ Bw^T.  BM x BN tile, BK=64 (128B full-line staging),
// 4 waves (2x2), 2-buffer LDS, counted-vmcnt two-barrier loop — sync
// structure verified R11/R13 (passed replays). R14: BN templated so both
// GEMMs get EVEN blocks/CU (parameter-lane change only, no sync edits):
//   gemm1 64x128 -> 768 blocks = 3/CU even (was 384 = 1.5/CU, pinned-block
//   imbalance ~25-33% makespan); gemm2 64x64 -> 512 = 2/CU (was 1/CU: every
//   vmcnt+barrier drain fully exposed, no co-resident block to overlap).
// vmcnt after STAGE(t+1) = AG+BG outstanding (tile t fully landed).
// Rule-#21 swizzle both-sides. XCD supertile mapping (neutral, kept).
// EPI=0: fp32 C. EPI=1: scatter Q(pre-scaled 0.125*log2e)/K/Vt bf16.
// ---------------------------------------------------------------------------
template<int BM, int BN, int M, int N, int K, int EPI, int CHM, int CHN>
__global__ __launch_bounds__(256)
void gemm_bt2(const unsigned short* __restrict__ A, const unsigned short* __restrict__ Bw,
              float* __restrict__ C, unsigned short* __restrict__ Qb,
              unsigned short* __restrict__ Kb, unsigned short* __restrict__ Vtb) {
  constexpr int NBN   = N / BN;
  constexpr int MT    = BM / 32;          // M-frags per wave
  constexpr int NT    = BN / 32;          // N-frags per wave
  constexpr int AG    = BM / 32;          // A-stage instrs per thread
  constexpr int BG    = BN / 32;          // B-stage instrs per thread
  constexpr int NSTEP = K / 64;
  constexpr int PM    = (M/BM) / CHM;     // supertile dims per XCD chunk
  constexpr int PN    = NBN / CHN;
  __shared__ unsigned short As[2][BM*64];
  __shared__ unsigned short Bs[2][BN*64];
  const int tid = threadIdx.x;
  const int xcd = blockIdx.x & 7, idx = blockIdx.x >> 3;
  const int mb = (xcd / CHN)*PM + idx / PN;
  const int nb = (xcd % CHN)*PN + idx % PN;
  const int wid = tid >> 6, lane = tid & 63;
  const int wr = wid >> 1, wc = wid & 1;
  const int lg = lane >> 4, lr = lane & 15;
  const int mrow = mb*BM, nrow = nb*BN;
  const int rsw = lr & 7;

  const int srow = tid >> 3;                    // 0..31
  const int cg   = (tid & 7) ^ (srow & 7);      // pre-swizzled global chunk

  f32x4 acc[MT][NT] = {};

  auto STAGE = [&](int t) {
    const int k0 = t*64, b = t & 1;
    #pragma unroll
    for (int g = 0; g < AG; ++g)
      gload_lds16(A + (size_t)(mrow + g*32 + srow)*K + k0 + cg*8,
                  &As[b][((g*32 + srow)*8 + (tid & 7))*8]);
    #pragma unroll
    for (int g = 0; g < BG; ++g)
      gload_lds16(Bw + (size_t)(nrow + g*32 + srow)*K + k0 + cg*8,
                  &Bs[b][((g*32 + srow)*8 + (tid & 7))*8]);
  };

  STAGE(0);
  for (int t = 0; t < NSTEP; ++t) {
    if (t + 1 < NSTEP) {
      STAGE(t+1);
      if constexpr (AG + BG == 8)      asm volatile("s_waitcnt vmcnt(8)" ::: "memory");
      else if constexpr (AG + BG == 6) asm volatile("s_waitcnt vmcnt(6)" ::: "memory");
      else                             asm volatile("s_waitcnt vmcnt(4)" ::: "memory");
    } else {
      asm volatile("s_waitcnt vmcnt(0)" ::: "memory");
    }
    __builtin_amdgcn_s_barrier();
    __builtin_amdgcn_sched_barrier(0);
    const int b = t & 1;
    #pragma unroll
    for (int kk = 0; kk < 2; ++kk) {
      bf16x8 af[MT], bfr[NT];
      #pragma unroll
      for (int m = 0; m < MT; ++m)
        af[m] = *(const bf16x8*)&As[b][(wr*(BM/2) + m*16 + lr)*64 + (((kk*4 + lg) ^ rsw)*8)];
      #pragma unroll
      for (int n = 0; n < NT; ++n)
        bfr[n] = *(const bf16x8*)&Bs[b][(wc*(BN/2) + n*16 + lr)*64 + (((kk*4 + lg) ^ rsw)*8)];
      #pragma unroll
      for (int m = 0; m < MT; ++m)
        #pragma unroll
        for (int n = 0; n < NT; ++n)
          acc[m][n] = __builtin_amdgcn_mfma_f32_16x16x32_bf16(af[m], bfr[n], acc[m][n], 0, 0, 0);
    }
    __builtin_amdgcn_sched_barrier(0);
    __builtin_amdgcn_s_barrier();
  }

  // Epilogue. C/D layout: row = lg*4 + i, col = lr  (verified m89/m91).
  #pragma unroll
  for (int mt = 0; mt < MT; ++mt) {
    const int m0 = mrow + wr*(BM/2) + mt*16 + lg*4;
    #pragma unroll
    for (int nt = 0; nt < NT; ++nt) {
      const int n = nrow + wc*(BN/2) + nt*16 + lr;
      f32x4 v = acc[mt][nt];
      if constexpr (EPI == 0) {
        #pragma unroll
        for (int i = 0; i < 4; ++i) C[(size_t)(m0 + i)*N + n] = v[i];
      } else {
        const int t3 = n >> 10, rem = n & 1023;
        const int hh = rem >> 6, dh = rem & 63;
        const int b = m0 >> 10, s0 = m0 & 1023;
        if (t3 == 2) {
          ushort4 pk;
          pk.x = f2bf(v[0]); pk.y = f2bf(v[1]); pk.z = f2bf(v[2]); pk.w = f2bf(v[3]);
          *(ushort4*)&Vtb[(size_t)((b*H_ + hh)*DH_ + dh)*S_ + s0] = pk;
        } else {
          unsigned short* dst = (t3 == 0) ? Qb : Kb;
          const float sc = (t3 == 0) ? 0.18033688f : 1.0f;   // 0.125 * log2(e)
          #pragma unroll
          for (int i = 0; i < 4; ++i)
            dst[(size_t)((b*H_ + hh)*S_ + s0 + i)*DH_ + dh] = f2bf(v[i]*sc);
        }
      }
    }
  }
}

// ---------------------------------------------------------------------------
// Flash attention v7 — EXACT R11/R13-verified sync structure (3-buffer
// counted vmcnt(4), STAGE(t+2), one barrier/iter; passed replay validation
// R7/R10/R11/R13). FROZEN — no edits this round.
// Max-free exp2 softmax (scale+log2e folded into Q), l via ones-MFMA,
// P packed with v_cvt_pk_bf16_f32, swapped QK^T / PV, XCD head swizzle.
// ---------------------------------------------------------------------------
__global__ __launch_bounds__(256, 2)
void attn_kernel(const unsigned short* __restrict__ Qb, const unsigned short* __restrict__ Kb,
                 const unsigned short* __restrict__ Vtb, unsigned short* __restrict__ AOb) {
  __shared__ unsigned short Ks[3][64*64];
  __shared__ unsigned short Vs[3][64*64];
  __shared__ unsigned short Pl[4][16*72];
  const int bid = blockIdx.x;
  const int xcd = bid & 7, rr = bid >> 3;
  const int qt = rr & 15;
  const int bh = (rr >> 4) * 8 + xcd;
  const int tid = threadIdx.x, wid = tid >> 6, lane = tid & 63;
  const int lg = lane >> 4, lr = lane & 15;
  const unsigned short* Q  = Qb  + (size_t)bh*S_*DH_;
  const unsigned short* Kp = Kb  + (size_t)bh*S_*DH_;
  const unsigned short* Vt = Vtb + (size_t)bh*DH_*S_;
  const int q0 = qt*64 + wid*16;

  bf16x8 qf0 = *(const bf16x8*)&Q[(size_t)(q0 + lr)*DH_ + lg*8];
  bf16x8 qf1 = *(const bf16x8*)&Q[(size_t)(q0 + lr)*DH_ + 32 + lg*8];
  const bf16x8 onesf = {(short)0x3F80, (short)0x3F80, (short)0x3F80, (short)0x3F80,
                        (short)0x3F80, (short)0x3F80, (short)0x3F80, (short)0x3F80};

  const int sr = tid >> 3;               // 0..31
  const int g0 = (tid & 7) ^ (sr & 7);   // pre-swizzled source chunk

  f32x4 o[4] = {};
  f32x4 ol = {};                         // l accumulator (all rows identical)
  const int rsw = lr & 7;

  auto STAGE = [&](int t) {
    const int j = t * 64, b = t % 3;
    gload_lds16(Kp + (size_t)(j + sr)*DH_      + g0*8, &Ks[b][tid*8]);
    gload_lds16(Kp + (size_t)(j + sr + 32)*DH_ + g0*8, &Ks[b][(256+tid)*8]);
    gload_lds16(Vt + (size_t)sr*S_      + j + g0*8,    &Vs[b][tid*8]);
    gload_lds16(Vt + (size_t)(sr+32)*S_ + j + g0*8,    &Vs[b][(256+tid)*8]);
  };

  STAGE(0);
  STAGE(1);
  for (int t = 0; t < 16; ++t) {
    if (t < 15) asm volatile("s_waitcnt vmcnt(4)" ::: "memory");
    else        asm volatile("s_waitcnt vmcnt(0)" ::: "memory");
    __builtin_amdgcn_s_barrier();
    __builtin_amdgcn_sched_barrier(0);
    if (t + 2 < 16) STAGE(t+2);
    const int buf = t % 3;
    // QK^T swapped: sv[f] = S^T rows (keys) 16f+lg*4+i, col q=lr
    f32x4 sv[4];
    __builtin_amdgcn_s_setprio(1);
    #pragma unroll
    for (int f = 0; f < 4; ++f) {
      bf16x8 ka = *(const bf16x8*)&Ks[buf][(16*f + lr)*64 + ((lg     ^ rsw)*8)];
      bf16x8 kb = *(const bf16x8*)&Ks[buf][(16*f + lr)*64 + (((lg+4) ^ rsw)*8)];
      f32x4 z = {};
      z     = __builtin_amdgcn_mfma_f32_16x16x32_bf16(ka, qf0, z, 0, 0, 0);
      sv[f] = __builtin_amdgcn_mfma_f32_16x16x32_bf16(kb, qf1, z, 0, 0, 0);
    }
    __builtin_amdgcn_s_setprio(0);
    // max-free softmax: P = 2^(s') directly (Q pre-scaled by 0.125*log2e)
    float p[16];
    #pragma unroll
    for (int f = 0; f < 4; ++f)
      #pragma unroll
      for (int i = 0; i < 4; ++i)
        asm("v_exp_f32 %0, %1" : "=v"(p[4*f + i]) : "v"(sv[f][i]));
    // P^T pack -> Pl[q=lr][key] via v_cvt_pk_bf16_f32
    #pragma unroll
    for (int f = 0; f < 4; ++f) {
      unsigned int w0, w1;
      asm("v_cvt_pk_bf16_f32 %0, %1, %2" : "=v"(w0) : "v"(p[4*f+0]), "v"(p[4*f+1]));
      asm("v_cvt_pk_bf16_f32 %0, %1, %2" : "=v"(w1) : "v"(p[4*f+2]), "v"(p[4*f+3]));
      uint2 wv; wv.x = w0; wv.y = w1;
      *(uint2*)&Pl[wid][lr*72 + f*16 + lg*4] = wv;
    }
    asm volatile("s_waitcnt lgkmcnt(0)" ::: "memory");
    __builtin_amdgcn_sched_barrier(0);
    // PV swapped: o[dt] += Vs[d][k] * P^T[k][q];  l via ones-MFMA
    __builtin_amdgcn_s_setprio(1);
    #pragma unroll
    for (int c = 0; c < 2; ++c) {
      bf16x8 pf = *(const bf16x8*)&Pl[wid][lr*72 + c*32 + lg*8];
      ol = __builtin_amdgcn_mfma_f32_16x16x32_bf16(onesf, pf, ol, 0, 0, 0);
      #pragma unroll
      for (int dt = 0; dt < 4; ++dt) {
        bf16x8 vfr = *(const bf16x8*)&Vs[buf][(dt*16 + lr)*64 + (((c*4 + lg) ^ rsw)*8)];
        o[dt] = __builtin_amdgcn_mfma_f32_16x16x32_bf16(vfr, pf, o[dt], 0, 0, 0);
      }
    }
    __builtin_amdgcn_s_setprio(0);
  }

  // epilogue: lane holds O^T[d = dt*16+lg*4+i][q = q0+lr]; l = ol[0]
  const float inv = 1.0f / ol[0];
  const int b = bh >> 4, hh = bh & 15;
  #pragma unroll
  for (int dt = 0; dt < 4; ++dt) {
    ushort4 pk;
    pk.x = f2bf(o[dt][0]*inv); pk.y = f2bf(o[dt][1]*inv);
    pk.z = f2bf(o[dt][2]*inv); pk.w = f2bf(o[dt][3]*inv);
    *(ushort4*)&AOb[(size_t)(b*S_ + q0 + lr)*D_ + hh*DH_ + dt*16 + lg*4] = pk;
  }
}

// ---------------------------------------------------------------------------
extern "C" void kernel_launch(void* const* d_in, const int* in_sizes, int n_in,
                              void* d_out, int out_size, void* d_ws, size_t ws_size,
                              hipStream_t stream) {
  const float* x  = (const float*)d_in[0];   // [B,S,D]
  const float* wq = (const float*)d_in[1];   // [3D,D]
  const float* wo = (const float*)d_in[2];   // [D,D]
  float* out = (float*)d_out;                // [B,S,D] fp32

  unsigned short* w = (unsigned short*)d_ws;
  unsigned short* xb  = w;                   // 2097152 bf16
  unsigned short* wqb = xb  + 2097152;       // 3145728
  unsigned short* wob = wqb + 3145728;       // 1048576
  unsigned short* qb  = wob + 1048576;       // 2097152  Q [B,H,S,DH] (pre-scaled)
  unsigned short* kb  = qb  + 2097152;       // 2097152  K [B,H,S,DH]
  unsigned short* vtb = kb  + 2097152;       // 2097152  V^T [B,H,DH,S]
  unsigned short* aob = vtb + 2097152;       // 2097152  attn out [B,S,D]

  cvt_kernel<<<dim3(1536), dim3(256), 0, stream>>>(
      (const float4*)x, (const float4*)wq, (const float4*)wo, xb, wqb, wob);

  // QKV projection: M=2048, N=3072, K=1024. 64x128 tiles -> 32x24 = 768
  // blocks = 3/CU EVEN (12 waves/CU). XCD chunk 2x4, supertile 16x6.
  gemm_bt2<64, 128, 2048, 3072, 1024, 1, 2, 4><<<dim3(768), dim3(256), 0, stream>>>(
      xb, wqb, nullptr, qb, kb, vtb);

  attn_kernel<<<dim3(512), dim3(256), 0, stream>>>(qb, kb, vtb, aob);

  // Output projection: M=2048, N=1024, K=1024. 64x64 tiles -> 32x16 = 512
  // blocks = 2/CU EVEN (barrier drains overlap across blocks).
  // XCD chunk 4x2, supertile 8x8.
  gemm_bt2<64, 64, 2048, 1024, 1024, 0, 4, 2><<<dim3(512), dim3(256), 0, stream>>>(
      aob, wob, out, nullptr, nullptr, nullptr);
}